// Round 2
// baseline (169.025 us; speedup 1.0000x reference)
//
#include <hip/hip_runtime.h>
#include <math.h>

#define HW 262144   // 512*512 elements per batch
#define BPB 64      // blocks per batch
#define CHUNK 4096  // elements per block (HW / BPB)
// per thread: CHUNK/256 = 16 elements = 4 float4 per input array

// Monotonic unsigned mapping of float bits: preserves ordering for all
// finite floats (negatives flipped, positives offset).
__device__ __forceinline__ unsigned int fmono(float f) {
    unsigned int u = __float_as_uint(f);
    return (u & 0x80000000u) ? ~u : (u | 0x80000000u);
}

__global__ __launch_bounds__(256) void reduce_kernel(
    const float* __restrict__ pred, const float* __restrict__ label,
    unsigned long long* __restrict__ pp, unsigned long long* __restrict__ lp,
    float* __restrict__ mse)
{
    const int bi = blockIdx.x;
    const int b = bi >> 6;            // batch
    const int chunk = bi & (BPB - 1);
    const float4* p4 = (const float4*)(pred + (size_t)b * HW) + (size_t)chunk * (CHUNK / 4);
    const float4* l4 = (const float4*)(label + (size_t)b * HW) + (size_t)chunk * (CHUNK / 4);
    const int t = threadIdx.x;
    const unsigned int base = (unsigned int)chunk * CHUNK;

    // Issue ALL global loads before any use: 8 independent 16B loads in
    // flight per thread (memory-level parallelism — we are latency-bound,
    // not BW-bound). ~32 data VGPRs, stays under the 64-VGPR occupancy cliff.
    float4 P[4], L[4];
#pragma unroll
    for (int i = 0; i < 4; ++i) {
        P[i] = p4[i * 256 + t];
        L[i] = l4[i * 256 + t];
    }

    float sumsq = 0.0f;
    float pmax = -INFINITY, lmax = -INFINITY;
    unsigned int pidx = 0, lidx = 0;

#pragma unroll
    for (int i = 0; i < 4; ++i) {
        const float4 p = P[i];
        const float4 l = L[i];
        const unsigned int e = base + ((unsigned int)(i * 256 + t)) * 4;
        float d;
        d = p.x - l.x; sumsq += d * d;
        d = p.y - l.y; sumsq += d * d;
        d = p.z - l.z; sumsq += d * d;
        d = p.w - l.w; sumsq += d * d;
        // strict > keeps the first (lowest-index) occurrence within a thread
        if (p.x > pmax) { pmax = p.x; pidx = e;     }
        if (p.y > pmax) { pmax = p.y; pidx = e + 1; }
        if (p.z > pmax) { pmax = p.z; pidx = e + 2; }
        if (p.w > pmax) { pmax = p.w; pidx = e + 3; }
        if (l.x > lmax) { lmax = l.x; lidx = e;     }
        if (l.y > lmax) { lmax = l.y; lidx = e + 1; }
        if (l.z > lmax) { lmax = l.z; lidx = e + 2; }
        if (l.w > lmax) { lmax = l.w; lidx = e + 3; }
    }

    // pack: high 32 = monotonic value bits, low 32 = ~index so that on value
    // tie the LOWER index wins under unsigned max (matches jnp.argmax).
    unsigned long long ppk = ((unsigned long long)fmono(pmax) << 32) | (unsigned long long)(0xFFFFFFFFu - pidx);
    unsigned long long lpk = ((unsigned long long)fmono(lmax) << 32) | (unsigned long long)(0xFFFFFFFFu - lidx);

    // wave(64) shuffle reduction
    for (int off = 32; off > 0; off >>= 1) {
        sumsq += __shfl_down(sumsq, off);
        unsigned long long o;
        o = __shfl_down(ppk, off); if (o > ppk) ppk = o;
        o = __shfl_down(lpk, off); if (o > lpk) lpk = o;
    }

    __shared__ float s_sum[4];
    __shared__ unsigned long long s_pp[4], s_lp[4];
    const int wave = t >> 6, lane = t & 63;
    if (lane == 0) { s_sum[wave] = sumsq; s_pp[wave] = ppk; s_lp[wave] = lpk; }
    __syncthreads();
    if (t == 0) {
        float s = s_sum[0] + s_sum[1] + s_sum[2] + s_sum[3];
        unsigned long long P2 = s_pp[0], L2 = s_lp[0];
        #pragma unroll
        for (int i = 1; i < 4; ++i) {
            if (s_pp[i] > P2) P2 = s_pp[i];
            if (s_lp[i] > L2) L2 = s_lp[i];
        }
        atomicAdd(mse, s);
        atomicMax(&pp[b], P2);
        atomicMax(&lp[b], L2);
    }
}

__global__ void finalize_kernel(const unsigned long long* __restrict__ pp,
                                const unsigned long long* __restrict__ lp,
                                const float* __restrict__ mse,
                                float* __restrict__ out)
{
    const int i = threadIdx.x;  // 0..63, one lane per batch
    const unsigned int ip = 0xFFFFFFFFu - (unsigned int)(pp[i] & 0xFFFFFFFFull);
    const unsigned int il = 0xFFFFFFFFu - (unsigned int)(lp[i] & 0xFFFFFFFFull);
    const float rp = (float)(ip >> 9), cp = (float)(ip & 511u);
    const float rl = (float)(il >> 9), cl = (float)(il & 511u);
    float d = (rp - rl) * (rp - rl) + (cp - cl) * (cp - cl);
    for (int off = 32; off > 0; off >>= 1) d += __shfl_down(d, off);
    if (i == 0) {
        const float m = *mse;
        const float alpha = (d != 0.0f) ? (m / d) : 1.0f;
        out[0] = (m + 0.25f * alpha * d) / 64.0f;
    }
}

extern "C" void kernel_launch(void* const* d_in, const int* in_sizes, int n_in,
                              void* d_out, int out_size, void* d_ws, size_t ws_size,
                              hipStream_t stream) {
    const float* pred  = (const float*)d_in[0];
    const float* label = (const float*)d_in[1];
    float* out = (float*)d_out;

    unsigned long long* pp = (unsigned long long*)d_ws;   // 64 packed pred argmax
    unsigned long long* lp = pp + 64;                     // 64 packed label argmax
    float* mse = (float*)(lp + 64);                       // 1 float mse accumulator

    // ws is poisoned 0xAA before every launch; zero the part we use.
    hipMemsetAsync(d_ws, 0, 2 * 64 * sizeof(unsigned long long) + sizeof(float), stream);

    reduce_kernel<<<dim3(64 * BPB), dim3(256), 0, stream>>>(pred, label, pp, lp, mse);
    finalize_kernel<<<dim3(1), dim3(64), 0, stream>>>(pp, lp, mse, out);
}

// Round 3
// 143.183 us; speedup vs baseline: 1.1805x; 1.1805x over previous
//
#include <hip/hip_runtime.h>
#include <math.h>

#define HW 262144   // 512*512 elements per batch
#define BPB 32      // blocks per batch
#define CHUNK 8192  // elements per block; per thread 32 elements = 8 float4 per input
#define NBLK (64 * BPB)  // 2048 blocks

// Monotonic unsigned mapping of float bits: preserves ordering for all
// finite floats (negatives flipped, positives offset).
__device__ __forceinline__ unsigned int fmono(float f) {
    unsigned int u = __float_as_uint(f);
    return (u & 0x80000000u) ? ~u : (u | 0x80000000u);
}

__global__ __launch_bounds__(256) void reduce_kernel(
    const float* __restrict__ pred, const float* __restrict__ label,
    unsigned long long* __restrict__ pblk, unsigned long long* __restrict__ lblk,
    float* __restrict__ sblk)
{
    const int bi = blockIdx.x;
    const int b = bi >> 5;            // batch
    const int chunk = bi & (BPB - 1);
    const float4* p4 = (const float4*)(pred + (size_t)b * HW) + (size_t)chunk * (CHUNK / 4);
    const float4* l4 = (const float4*)(label + (size_t)b * HW) + (size_t)chunk * (CHUNK / 4);
    const int t = threadIdx.x;
    const unsigned int base = (unsigned int)chunk * CHUNK;

    // Issue ALL 16 global loads as one clause, then compute. sched_barrier(0)
    // pins the boundary — R2 showed the compiler otherwise sinks loads next
    // to uses (VGPR=24 => ~2 loads in flight => ~2-3 TB/s latency-bound).
    // 256 B/thread in flight is the point of this kernel.
    float4 P[8], L[8];
#pragma unroll
    for (int i = 0; i < 8; ++i) P[i] = p4[i * 256 + t];
#pragma unroll
    for (int i = 0; i < 8; ++i) L[i] = l4[i * 256 + t];
    __builtin_amdgcn_sched_barrier(0);

    float sumsq = 0.0f;
    float pmax = -INFINITY, lmax = -INFINITY;
    unsigned int pidx = 0, lidx = 0;

#pragma unroll
    for (int i = 0; i < 8; ++i) {
        const float4 p = P[i];
        const float4 l = L[i];
        const unsigned int e = base + ((unsigned int)(i * 256 + t)) * 4;
        float d;
        d = p.x - l.x; sumsq += d * d;
        d = p.y - l.y; sumsq += d * d;
        d = p.z - l.z; sumsq += d * d;
        d = p.w - l.w; sumsq += d * d;
        // strict > keeps the first (lowest-index) occurrence within a thread
        if (p.x > pmax) { pmax = p.x; pidx = e;     }
        if (p.y > pmax) { pmax = p.y; pidx = e + 1; }
        if (p.z > pmax) { pmax = p.z; pidx = e + 2; }
        if (p.w > pmax) { pmax = p.w; pidx = e + 3; }
        if (l.x > lmax) { lmax = l.x; lidx = e;     }
        if (l.y > lmax) { lmax = l.y; lidx = e + 1; }
        if (l.z > lmax) { lmax = l.z; lidx = e + 2; }
        if (l.w > lmax) { lmax = l.w; lidx = e + 3; }
    }

    // pack: high 32 = monotonic value bits, low 32 = ~index so that on value
    // tie the LOWER index wins under unsigned max (matches jnp.argmax).
    unsigned long long ppk = ((unsigned long long)fmono(pmax) << 32) | (unsigned long long)(0xFFFFFFFFu - pidx);
    unsigned long long lpk = ((unsigned long long)fmono(lmax) << 32) | (unsigned long long)(0xFFFFFFFFu - lidx);

    // wave(64) shuffle reduction
    for (int off = 32; off > 0; off >>= 1) {
        sumsq += __shfl_down(sumsq, off);
        unsigned long long o;
        o = __shfl_down(ppk, off); if (o > ppk) ppk = o;
        o = __shfl_down(lpk, off); if (o > lpk) lpk = o;
    }

    __shared__ float s_sum[4];
    __shared__ unsigned long long s_pp[4], s_lp[4];
    const int wave = t >> 6, lane = t & 63;
    if (lane == 0) { s_sum[wave] = sumsq; s_pp[wave] = ppk; s_lp[wave] = lpk; }
    __syncthreads();
    if (t == 0) {
        float s = s_sum[0] + s_sum[1] + s_sum[2] + s_sum[3];
        unsigned long long P2 = s_pp[0], L2 = s_lp[0];
#pragma unroll
        for (int i = 1; i < 4; ++i) {
            if (s_pp[i] > P2) P2 = s_pp[i];
            if (s_lp[i] > L2) L2 = s_lp[i];
        }
        // Atomic-free: every block writes its own slot -> no memset needed,
        // no contention. Finalize kernel does the cross-block reduction.
        pblk[bi] = P2;
        lblk[bi] = L2;
        sblk[bi] = s;
    }
}

// One block, 1024 threads: reduces 2048 per-block partials.
// Threads t: batch = t>>4, j = t&15 covers chunk partials j and j+16 (32/batch).
__global__ __launch_bounds__(1024) void finalize_kernel(
    const unsigned long long* __restrict__ pblk,
    const unsigned long long* __restrict__ lblk,
    const float* __restrict__ sblk,
    float* __restrict__ out)
{
    const int t = threadIdx.x;  // 0..1023

    // global mse: sum of all 2048 partials
    float s = sblk[t] + sblk[t + 1024];
    for (int off = 32; off > 0; off >>= 1) s += __shfl_down(s, off);
    __shared__ float ss[16];
    const int wave = t >> 6;
    if ((t & 63) == 0) ss[wave] = s;

    // per-batch argmax over 32 chunk partials
    const int batch = t >> 4, j = t & 15;
    unsigned long long Pv = pblk[batch * 32 + j];
    unsigned long long o  = pblk[batch * 32 + j + 16];
    if (o > Pv) Pv = o;
    unsigned long long Lv = lblk[batch * 32 + j];
    o = lblk[batch * 32 + j + 16];
    if (o > Lv) Lv = o;
    for (int off = 8; off > 0; off >>= 1) {
        o = __shfl_down(Pv, off, 16); if (o > Pv) Pv = o;
        o = __shfl_down(Lv, off, 16); if (o > Lv) Lv = o;
    }
    __shared__ float dd[64];
    if (j == 0) {
        const unsigned int ip = 0xFFFFFFFFu - (unsigned int)(Pv & 0xFFFFFFFFull);
        const unsigned int il = 0xFFFFFFFFu - (unsigned int)(Lv & 0xFFFFFFFFull);
        const float rp = (float)(ip >> 9), cp = (float)(ip & 511u);
        const float rl = (float)(il >> 9), cl = (float)(il & 511u);
        dd[batch] = (rp - rl) * (rp - rl) + (cp - cl) * (cp - cl);
    }
    __syncthreads();
    if (t < 64) {
        float d = dd[t];
        for (int off = 32; off > 0; off >>= 1) d += __shfl_down(d, off);
        if (t == 0) {
            float m = 0.0f;
#pragma unroll
            for (int i = 0; i < 16; ++i) m += ss[i];
            const float alpha = (d != 0.0f) ? (m / d) : 1.0f;
            out[0] = (m + 0.25f * alpha * d) / 64.0f;
        }
    }
}

extern "C" void kernel_launch(void* const* d_in, const int* in_sizes, int n_in,
                              void* d_out, int out_size, void* d_ws, size_t ws_size,
                              hipStream_t stream) {
    const float* pred  = (const float*)d_in[0];
    const float* label = (const float*)d_in[1];
    float* out = (float*)d_out;

    unsigned long long* pblk = (unsigned long long*)d_ws;  // 2048 packed pred argmax
    unsigned long long* lblk = pblk + NBLK;                // 2048 packed label argmax
    float* sblk = (float*)(lblk + NBLK);                   // 2048 mse partials

    // No memset: every workspace slot is written unconditionally by its block.
    reduce_kernel<<<dim3(NBLK), dim3(256), 0, stream>>>(pred, label, pblk, lblk, sblk);
    finalize_kernel<<<dim3(1), dim3(1024), 0, stream>>>(pblk, lblk, sblk, out);
}

// Round 4
// 143.081 us; speedup vs baseline: 1.1813x; 1.0007x over previous
//
#include <hip/hip_runtime.h>
#include <math.h>

#define HW 262144   // 512*512 elements per batch
#define BPB 32      // blocks per batch
#define CHUNK 8192  // elements per block; per thread 32 elements = 8 float4 per input
#define NBLK (64 * BPB)  // 2048 blocks

typedef float f4 __attribute__((ext_vector_type(4)));

// Async 16B load: SGPR base pair + VGPR byte offset. The compiler's waitcnt
// pass does NOT track these — we wait manually below. This is the only way
// to keep 16 loads/thread in flight (R1-R3: compiler pins to ~2).
#define GLOAD(dst, voff, base)                                   \
    asm volatile("global_load_dwordx4 %0, %1, %2"                \
                 : "=v"(dst) : "v"(voff), "s"(base))

// Monotonic unsigned mapping of float bits: preserves ordering for all
// finite floats (negatives flipped, positives offset).
__device__ __forceinline__ unsigned int fmono(float f) {
    unsigned int u = __float_as_uint(f);
    return (u & 0x80000000u) ? ~u : (u | 0x80000000u);
}

__global__ __launch_bounds__(256) void reduce_kernel(
    const float* __restrict__ pred, const float* __restrict__ label,
    unsigned long long* __restrict__ pblk, unsigned long long* __restrict__ lblk,
    float* __restrict__ sblk)
{
    const int bi = blockIdx.x;
    const int b = bi >> 5;            // batch
    const int chunk = bi & (BPB - 1);
    const float* pbase = pred  + (size_t)b * HW + (size_t)chunk * CHUNK;
    const float* lbase = label + (size_t)b * HW + (size_t)chunk * CHUNK;
    const int t = threadIdx.x;
    const unsigned int base = (unsigned int)chunk * CHUNK;
    const unsigned int voff = (unsigned int)t * 16u;   // byte offset within 4KB stripe

    f4 P0,P1,P2,P3,P4,P5,P6,P7, L0,L1,L2,L3,L4,L5,L6,L7;
    // Issue order matters for the vmcnt(8) below: first 8 = P0-3,L0-3.
    GLOAD(P0, voff, pbase + 0*1024); GLOAD(P1, voff, pbase + 1*1024);
    GLOAD(P2, voff, pbase + 2*1024); GLOAD(P3, voff, pbase + 3*1024);
    GLOAD(L0, voff, lbase + 0*1024); GLOAD(L1, voff, lbase + 1*1024);
    GLOAD(L2, voff, lbase + 2*1024); GLOAD(L3, voff, lbase + 3*1024);
    GLOAD(P4, voff, pbase + 4*1024); GLOAD(P5, voff, pbase + 5*1024);
    GLOAD(P6, voff, pbase + 6*1024); GLOAD(P7, voff, pbase + 7*1024);
    GLOAD(L4, voff, lbase + 4*1024); GLOAD(L5, voff, lbase + 5*1024);
    GLOAD(L6, voff, lbase + 6*1024); GLOAD(L7, voff, lbase + 7*1024);

    float sumsq = 0.0f;
    float pmax = -INFINITY, lmax = -INFINITY;
    unsigned int pidx = 0, lidx = 0;

#define STEP(p, l, i)                                                         \
    do {                                                                      \
        const unsigned int e = base + ((unsigned int)((i) * 256 + t)) * 4u;   \
        float d;                                                              \
        d = p[0] - l[0]; sumsq += d * d;                                      \
        d = p[1] - l[1]; sumsq += d * d;                                      \
        d = p[2] - l[2]; sumsq += d * d;                                      \
        d = p[3] - l[3]; sumsq += d * d;                                      \
        if (p[0] > pmax) { pmax = p[0]; pidx = e;      }                      \
        if (p[1] > pmax) { pmax = p[1]; pidx = e + 1u; }                      \
        if (p[2] > pmax) { pmax = p[2]; pidx = e + 2u; }                      \
        if (p[3] > pmax) { pmax = p[3]; pidx = e + 3u; }                      \
        if (l[0] > lmax) { lmax = l[0]; lidx = e;      }                      \
        if (l[1] > lmax) { lmax = l[1]; lidx = e + 1u; }                      \
        if (l[2] > lmax) { lmax = l[2]; lidx = e + 2u; }                      \
        if (l[3] > lmax) { lmax = l[3]; lidx = e + 3u; }                      \
    } while (0)

    // Wait until only 8 loads outstanding -> P0-3,L0-3 have landed. The "+v"
    // ties create the data dependence that keeps consumers below the wait.
    asm volatile("s_waitcnt vmcnt(8)"
        : "+v"(P0), "+v"(P1), "+v"(P2), "+v"(P3),
          "+v"(L0), "+v"(L1), "+v"(L2), "+v"(L3));
    STEP(P0, L0, 0); STEP(P1, L1, 1); STEP(P2, L2, 2); STEP(P3, L3, 3);

    asm volatile("s_waitcnt vmcnt(0)"
        : "+v"(P4), "+v"(P5), "+v"(P6), "+v"(P7),
          "+v"(L4), "+v"(L5), "+v"(L6), "+v"(L7));
    STEP(P4, L4, 4); STEP(P5, L5, 5); STEP(P6, L6, 6); STEP(P7, L7, 7);
#undef STEP

    // pack: high 32 = monotonic value bits, low 32 = ~index so that on value
    // tie the LOWER index wins under unsigned max (matches jnp.argmax).
    unsigned long long ppk = ((unsigned long long)fmono(pmax) << 32) | (unsigned long long)(0xFFFFFFFFu - pidx);
    unsigned long long lpk = ((unsigned long long)fmono(lmax) << 32) | (unsigned long long)(0xFFFFFFFFu - lidx);

    // wave(64) shuffle reduction
    for (int off = 32; off > 0; off >>= 1) {
        sumsq += __shfl_down(sumsq, off);
        unsigned long long o;
        o = __shfl_down(ppk, off); if (o > ppk) ppk = o;
        o = __shfl_down(lpk, off); if (o > lpk) lpk = o;
    }

    __shared__ float s_sum[4];
    __shared__ unsigned long long s_pp[4], s_lp[4];
    const int wave = t >> 6, lane = t & 63;
    if (lane == 0) { s_sum[wave] = sumsq; s_pp[wave] = ppk; s_lp[wave] = lpk; }
    __syncthreads();
    if (t == 0) {
        float s = s_sum[0] + s_sum[1] + s_sum[2] + s_sum[3];
        unsigned long long Pk = s_pp[0], Lk = s_lp[0];
#pragma unroll
        for (int i = 1; i < 4; ++i) {
            if (s_pp[i] > Pk) Pk = s_pp[i];
            if (s_lp[i] > Lk) Lk = s_lp[i];
        }
        // Atomic-free: every block writes its own slot (no memset needed).
        pblk[bi] = Pk;
        lblk[bi] = Lk;
        sblk[bi] = s;
    }
}

// One block, 1024 threads: reduces 2048 per-block partials.
__global__ __launch_bounds__(1024) void finalize_kernel(
    const unsigned long long* __restrict__ pblk,
    const unsigned long long* __restrict__ lblk,
    const float* __restrict__ sblk,
    float* __restrict__ out)
{
    const int t = threadIdx.x;  // 0..1023

    // global mse: sum of all 2048 partials
    float s = sblk[t] + sblk[t + 1024];
    for (int off = 32; off > 0; off >>= 1) s += __shfl_down(s, off);
    __shared__ float ss[16];
    const int wave = t >> 6;
    if ((t & 63) == 0) ss[wave] = s;

    // per-batch argmax over 32 chunk partials: batch = t>>4, j = t&15
    const int batch = t >> 4, j = t & 15;
    unsigned long long Pv = pblk[batch * 32 + j];
    unsigned long long o  = pblk[batch * 32 + j + 16];
    if (o > Pv) Pv = o;
    unsigned long long Lv = lblk[batch * 32 + j];
    o = lblk[batch * 32 + j + 16];
    if (o > Lv) Lv = o;
    for (int off = 8; off > 0; off >>= 1) {
        o = __shfl_down(Pv, off, 16); if (o > Pv) Pv = o;
        o = __shfl_down(Lv, off, 16); if (o > Lv) Lv = o;
    }
    __shared__ float dd[64];
    if (j == 0) {
        const unsigned int ip = 0xFFFFFFFFu - (unsigned int)(Pv & 0xFFFFFFFFull);
        const unsigned int il = 0xFFFFFFFFu - (unsigned int)(Lv & 0xFFFFFFFFull);
        const float rp = (float)(ip >> 9), cp = (float)(ip & 511u);
        const float rl = (float)(il >> 9), cl = (float)(il & 511u);
        dd[batch] = (rp - rl) * (rp - rl) + (cp - cl) * (cp - cl);
    }
    __syncthreads();
    if (t < 64) {
        float d = dd[t];
        for (int off = 32; off > 0; off >>= 1) d += __shfl_down(d, off);
        if (t == 0) {
            float m = 0.0f;
#pragma unroll
            for (int i = 0; i < 16; ++i) m += ss[i];
            const float alpha = (d != 0.0f) ? (m / d) : 1.0f;
            out[0] = (m + 0.25f * alpha * d) / 64.0f;
        }
    }
}

extern "C" void kernel_launch(void* const* d_in, const int* in_sizes, int n_in,
                              void* d_out, int out_size, void* d_ws, size_t ws_size,
                              hipStream_t stream) {
    const float* pred  = (const float*)d_in[0];
    const float* label = (const float*)d_in[1];
    float* out = (float*)d_out;

    unsigned long long* pblk = (unsigned long long*)d_ws;  // 2048 packed pred argmax
    unsigned long long* lblk = pblk + NBLK;                // 2048 packed label argmax
    float* sblk = (float*)(lblk + NBLK);                   // 2048 mse partials

    reduce_kernel<<<dim3(NBLK), dim3(256), 0, stream>>>(pred, label, pblk, lblk, sblk);
    finalize_kernel<<<dim3(1), dim3(1024), 0, stream>>>(pblk, lblk, sblk, out);
}